// Round 1
// baseline (619.357 us; speedup 1.0000x reference)
//
#include <hip/hip_runtime.h>

#define N_NODES 100000
#define N_EDGES 1600000
#define CH 64
#define NLAYERS 3

static __device__ __forceinline__ float4 ld4(const float* p){ return *(const float4*)p; }

// ---------------- CSR build ----------------
__global__ __launch_bounds__(256) void hist_kernel(const int* __restrict__ dst, int* __restrict__ cnt){
  int e = blockIdx.x*256 + threadIdx.x;
  if (e < N_EDGES) atomicAdd(&cnt[dst[e]], 1);
}

__global__ __launch_bounds__(256) void blocksum_kernel(const int* __restrict__ cnt, int* __restrict__ bsum){
  int i = blockIdx.x*256 + threadIdx.x;
  int v = (i < N_NODES) ? cnt[i] : 0;
  #pragma unroll
  for (int o = 32; o > 0; o >>= 1) v += __shfl_down(v, o, 64);
  __shared__ int sm[4];
  if ((threadIdx.x & 63) == 0) sm[threadIdx.x >> 6] = v;
  __syncthreads();
  if (threadIdx.x == 0) bsum[blockIdx.x] = sm[0]+sm[1]+sm[2]+sm[3];
}

__global__ __launch_bounds__(512) void scanb_kernel(int* __restrict__ bsum, int nb){
  __shared__ int s[512];
  int t = threadIdx.x;
  s[t] = (t < nb) ? bsum[t] : 0;
  __syncthreads();
  #pragma unroll
  for (int o = 1; o < 512; o <<= 1){
    int v = (t >= o) ? s[t-o] : 0;
    __syncthreads();
    s[t] += v;
    __syncthreads();
  }
  if (t < nb) bsum[t] = (t == 0) ? 0 : s[t-1];   // exclusive
}

__global__ __launch_bounds__(256) void offsets_kernel(const int* __restrict__ cnt, const int* __restrict__ bsum,
                                                      int* __restrict__ off){
  __shared__ int s[256];
  int t = threadIdx.x;
  int i = blockIdx.x*256 + t;
  int v = (i < N_NODES) ? cnt[i] : 0;
  s[t] = v; __syncthreads();
  #pragma unroll
  for (int o = 1; o < 256; o <<= 1){
    int u = (t >= o) ? s[t-o] : 0;
    __syncthreads();
    s[t] += u;
    __syncthreads();
  }
  if (i < N_NODES) {
    int base = bsum[blockIdx.x];
    off[i] = base + s[t] - v;                  // exclusive
    if (i == N_NODES-1) off[N_NODES] = base + s[t];
  }
}

__global__ __launch_bounds__(256) void fill_kernel(const int* __restrict__ src, const int* __restrict__ dst,
                                                   const int* __restrict__ off, int* __restrict__ cur,
                                                   int* __restrict__ srclist){
  int e = blockIdx.x*256 + threadIdx.x;
  if (e < N_EDGES) {
    int d = dst[e];
    int p = atomicAdd(&cur[d], 1);
    srclist[off[d] + p] = src[e];
  }
}

// ---------------- fold BN into weights/biases ----------------
// Wf layout: [L][2][64*64]; bf: [L][2][64]; ogb: og[L*64] then ob[L*64]
__global__ __launch_bounds__(256) void prep_kernel(
    const float* __restrict__ W1, const float* __restrict__ b1,
    const float* __restrict__ g1, const float* __restrict__ be1,
    const float* __restrict__ W2, const float* __restrict__ b2,
    const float* __restrict__ g2, const float* __restrict__ be2,
    const float* __restrict__ bng, const float* __restrict__ bnb,
    float* __restrict__ Wf, float* __restrict__ bf, float* __restrict__ ogb){
  const float s = 0.9999950000374997f;   // 1/sqrt(1+1e-5)
  int i = blockIdx.x*256 + threadIdx.x;
  if (i < NLAYERS*4096) {
    int l = i >> 12, rem = i & 4095, j = rem & 63;
    Wf[l*8192 + rem]        = W1[i] * g1[l*64+j] * s;
    Wf[l*8192 + 4096 + rem] = W2[i] * g2[l*64+j] * s;
  }
  if (i < NLAYERS*64) {
    int l = i >> 6, j = i & 63;
    bf[l*128 + j]      = b1[i]*g1[i]*s + be1[i];
    bf[l*128 + 64 + j] = b2[i]*g2[i]*s + be2[i];
    ogb[i]                 = bng[i]*s;
    ogb[NLAYERS*64 + i]    = bnb[i];
  }
}

// ---------------- aggregation: t[n] = (1+eps)*x[n] + sum_{e: dst=n} x[src[e]] ----------------
// 16 lanes per node, each lane owns 4 channels (float4).
__global__ __launch_bounds__(256) void agg_kernel(const float* __restrict__ x, const int* __restrict__ off,
                                                  const int* __restrict__ srclist, const float* __restrict__ eps,
                                                  int layer, float* __restrict__ t){
  int g = blockIdx.x*256 + threadIdx.x;
  int n = g >> 4;
  if (n >= N_NODES) return;
  int c = (g & 15) << 2;
  int e0 = off[n], e1 = off[n+1];
  float ax = 0.f, ay = 0.f, az = 0.f, aw = 0.f;
  for (int e = e0; e < e1; ++e) {
    int sidx = srclist[e];
    float4 v = ld4(x + (size_t)sidx*CH + c);
    ax += v.x; ay += v.y; az += v.z; aw += v.w;
  }
  float ep = 1.0f + eps[layer];
  float4 xv = ld4(x + (size_t)n*CH + c);
  float4 o = make_float4(fmaf(ep, xv.x, ax), fmaf(ep, xv.y, ay),
                         fmaf(ep, xv.z, az), fmaf(ep, xv.w, aw));
  *(float4*)(t + (size_t)n*CH + c) = o;
}

// ---------------- fused 2-layer MLP + outer BN (+optional ReLU) ----------------
// 64 nodes per block; 256 threads; thread tile = 4 nodes x 4 out-channels.
__global__ __launch_bounds__(256) void mlp_kernel(const float* __restrict__ t, const float* __restrict__ Wf,
                                                  const float* __restrict__ bf, const float* __restrict__ ogb,
                                                  int layer, float* __restrict__ out, int relu_out){
  __shared__ __align__(16) float W1s[64*64];
  __shared__ __align__(16) float W2s[64*64];
  __shared__ __align__(16) float Hs[64*68];   // +4 pad: spreads start banks, 2-way max (free)
  int tid = threadIdx.x;
  const float* Wg = Wf + layer*8192;
  #pragma unroll
  for (int it = 0; it < 4; ++it) {
    int i = (tid + it*256) * 4;
    *(float4*)&W1s[i] = ld4(Wg + i);
    *(float4*)&W2s[i] = ld4(Wg + 4096 + i);
  }
  long gbase = (long)blockIdx.x * 4096;
  #pragma unroll
  for (int it = 0; it < 4; ++it) {
    int idx = (tid + it*256) * 4;
    int nrow = idx >> 6, kk = idx & 63;
    float4 v = make_float4(0.f,0.f,0.f,0.f);
    if (gbase + idx < (long)N_NODES*CH) v = ld4(t + gbase + idx);
    *(float4*)&Hs[nrow*68 + kk] = v;
  }
  __syncthreads();

  int nq = (tid & 15) << 2;
  int j0 = (tid >> 4) << 2;
  const float4 bias1 = ld4(bf + layer*128 + j0);
  const float4 bias2 = ld4(bf + layer*128 + 64 + j0);
  const float4 og4   = ld4(ogb + layer*64 + j0);
  const float4 ob4   = ld4(ogb + NLAYERS*64 + layer*64 + j0);

  float acc[4][4];
  #pragma unroll
  for (int r = 0; r < 4; ++r){ acc[r][0]=bias1.x; acc[r][1]=bias1.y; acc[r][2]=bias1.z; acc[r][3]=bias1.w; }

  for (int k = 0; k < 64; k += 4) {
    float4 a[4], b[4];
    #pragma unroll
    for (int r = 0; r < 4; ++r) a[r] = *(const float4*)&Hs[(nq+r)*68 + k];
    #pragma unroll
    for (int kk = 0; kk < 4; ++kk) b[kk] = *(const float4*)&W1s[(k+kk)*64 + j0];
    #pragma unroll
    for (int r = 0; r < 4; ++r){
      const float* ar = (const float*)&a[r];
      #pragma unroll
      for (int kk = 0; kk < 4; ++kk){
        float av = ar[kk];
        acc[r][0] = fmaf(av, b[kk].x, acc[r][0]);
        acc[r][1] = fmaf(av, b[kk].y, acc[r][1]);
        acc[r][2] = fmaf(av, b[kk].z, acc[r][2]);
        acc[r][3] = fmaf(av, b[kk].w, acc[r][3]);
      }
    }
  }
  __syncthreads();   // all GEMM1 reads of Hs done
  #pragma unroll
  for (int r = 0; r < 4; ++r){
    float4 hv = make_float4(fmaxf(acc[r][0],0.f), fmaxf(acc[r][1],0.f),
                            fmaxf(acc[r][2],0.f), fmaxf(acc[r][3],0.f));
    *(float4*)&Hs[(nq+r)*68 + j0] = hv;
  }
  __syncthreads();

  #pragma unroll
  for (int r = 0; r < 4; ++r){ acc[r][0]=bias2.x; acc[r][1]=bias2.y; acc[r][2]=bias2.z; acc[r][3]=bias2.w; }
  for (int k = 0; k < 64; k += 4) {
    float4 a[4], b[4];
    #pragma unroll
    for (int r = 0; r < 4; ++r) a[r] = *(const float4*)&Hs[(nq+r)*68 + k];
    #pragma unroll
    for (int kk = 0; kk < 4; ++kk) b[kk] = *(const float4*)&W2s[(k+kk)*64 + j0];
    #pragma unroll
    for (int r = 0; r < 4; ++r){
      const float* ar = (const float*)&a[r];
      #pragma unroll
      for (int kk = 0; kk < 4; ++kk){
        float av = ar[kk];
        acc[r][0] = fmaf(av, b[kk].x, acc[r][0]);
        acc[r][1] = fmaf(av, b[kk].y, acc[r][1]);
        acc[r][2] = fmaf(av, b[kk].z, acc[r][2]);
        acc[r][3] = fmaf(av, b[kk].w, acc[r][3]);
      }
    }
  }

  #pragma unroll
  for (int r = 0; r < 4; ++r){
    int gnode = blockIdx.x*64 + nq + r;
    if (gnode < N_NODES) {
      float o0 = fmaf(og4.x, fmaxf(acc[r][0],0.f), ob4.x);
      float o1 = fmaf(og4.y, fmaxf(acc[r][1],0.f), ob4.y);
      float o2 = fmaf(og4.z, fmaxf(acc[r][2],0.f), ob4.z);
      float o3 = fmaf(og4.w, fmaxf(acc[r][3],0.f), ob4.w);
      if (relu_out){ o0=fmaxf(o0,0.f); o1=fmaxf(o1,0.f); o2=fmaxf(o2,0.f); o3=fmaxf(o3,0.f); }
      *(float4*)(out + (size_t)gnode*CH + j0) = make_float4(o0,o1,o2,o3);
    }
  }
}

extern "C" void kernel_launch(void* const* d_in, const int* in_sizes, int n_in,
                              void* d_out, int out_size, void* d_ws, size_t ws_size,
                              hipStream_t stream) {
  const float* x0  = (const float*)d_in[0];
  const int*   ei  = (const int*)d_in[1];
  const float* eps = (const float*)d_in[2];
  const float* W1  = (const float*)d_in[3];
  const float* b1  = (const float*)d_in[4];
  const float* g1  = (const float*)d_in[5];
  const float* be1 = (const float*)d_in[6];
  const float* W2  = (const float*)d_in[7];
  const float* b2  = (const float*)d_in[8];
  const float* g2  = (const float*)d_in[9];
  const float* be2 = (const float*)d_in[10];
  const float* bng = (const float*)d_in[11];
  const float* bnb = (const float*)d_in[12];
  const int* src = ei;
  const int* dst = ei + N_EDGES;
  float* OUT = (float*)d_out;

  // workspace carve (~33 MB total)
  char* p = (char*)d_ws;
  auto carve = [&](size_t bytes)->char*{ char* r = p; p += (bytes + 255) & ~(size_t)255; return r; };
  int*   off     = (int*)carve((N_NODES+1)*sizeof(int));
  int*   cnt     = (int*)carve((size_t)N_NODES*sizeof(int));
  int*   bsum    = (int*)carve(512*sizeof(int));
  int*   srclist = (int*)carve((size_t)N_EDGES*sizeof(int));
  float* T       = (float*)carve((size_t)N_NODES*CH*sizeof(float));
  float* Wf      = (float*)carve((size_t)NLAYERS*2*4096*sizeof(float));
  float* bfb     = (float*)carve((size_t)NLAYERS*2*64*sizeof(float));
  float* ogb     = (float*)carve((size_t)2*NLAYERS*64*sizeof(float));

  const int nb = (N_NODES + 255)/256;          // 391 blocks
  hipMemsetAsync(cnt, 0, (size_t)N_NODES*sizeof(int), stream);
  hist_kernel<<<N_EDGES/256, 256, 0, stream>>>(dst, cnt);
  blocksum_kernel<<<nb, 256, 0, stream>>>(cnt, bsum);
  scanb_kernel<<<1, 512, 0, stream>>>(bsum, nb);
  offsets_kernel<<<nb, 256, 0, stream>>>(cnt, bsum, off);
  hipMemsetAsync(cnt, 0, (size_t)N_NODES*sizeof(int), stream);
  fill_kernel<<<N_EDGES/256, 256, 0, stream>>>(src, dst, off, cnt, srclist);
  prep_kernel<<<48, 256, 0, stream>>>(W1,b1,g1,be1,W2,b2,g2,be2,bng,bnb,Wf,bfb,ogb);

  for (int l = 0; l < NLAYERS; ++l) {
    const float* xin = (l == 0) ? x0 : OUT;    // d_out doubles as the ping buffer
    agg_kernel<<<(N_NODES*16)/256, 256, 0, stream>>>(xin, off, srclist, eps, l, T);
    mlp_kernel<<<(N_NODES+63)/64, 256, 0, stream>>>(T, Wf, bfb, ogb, l, OUT, (l < NLAYERS-1) ? 1 : 0);
  }
}